// Round 8
// baseline (11755.694 us; speedup 1.0000x reference)
//
#include <hip/hip_runtime.h>
#include <stdint.h>

#define BDIM 256
#define SEQL 128
#define IND 512
#define HID 512
#define KDIM 1024 // IND + HID

// Activation buffer layout "A4": float A4[256][256][4] conceptually =
// [k_quad][batch][k_low]. Element (b,k) lives at (k>>2)*1024 + b*4 + (k&3).
// Gates lane b reads A4[kq]*1024 + b*4 as float4 -> 64 lanes x 16B = 1 KiB
// fully coalesced per wave instruction.

__device__ __forceinline__ float sigm(float x) { return 1.0f / (1.0f + __expf(-x)); }

// ---- init: h0,c0 from the zero-input zero-state cell (gates = bias) ----
__global__ void k_init(const float* __restrict__ b_ih, const float* __restrict__ b_hh,
                       float* __restrict__ c, float* __restrict__ A0) {
  int b = blockIdx.x;
  for (int j = threadIdx.x; j < HID; j += blockDim.x) {
    float bi = b_ih[j] + b_hh[j];
    float bg = b_ih[2 * HID + j] + b_hh[2 * HID + j];
    float bo = b_ih[3 * HID + j] + b_hh[3 * HID + j];
    float c0 = sigm(bi) * tanhf(bg);
    float h0 = sigm(bo) * tanhf(c0);
    c[b * HID + j] = c0;
    int k = IND + j;
    A0[(size_t)(k >> 2) * 1024 + b * 4 + (k & 3)] = h0;
  }
}

// ---- per step: attention logits -> softmax -> xi (into A4 layout) ----
__global__ __launch_bounds__(256) void k_attn(const float* __restrict__ c, const float* __restrict__ Wa,
                                              const float* __restrict__ ba, const float* __restrict__ x,
                                              float* __restrict__ A) {
  __shared__ float sc[HID];
  __shared__ float sl[SEQL];
  __shared__ float sxi[2][HID];
  int b = blockIdx.x, tid = threadIdx.x;
  sc[tid] = c[b * HID + tid];
  sc[tid + 256] = c[b * HID + tid + 256];
  __syncthreads();
  int wave = tid >> 6, lane = tid & 63;
  // logits: 4 waves x 32 rows, shuffle-reduced (proven)
  for (int si = 0; si < 32; ++si) {
    int s = wave * 32 + si;
    const float* wr = Wa + s * HID;
    float acc = 0.f;
#pragma unroll
    for (int it = 0; it < 8; ++it) {
      int k = lane + it * 64;
      acc += sc[k] * wr[k];
    }
#pragma unroll
    for (int off = 32; off > 0; off >>= 1) acc += __shfl_down(acc, off);
    if (lane == 0) sl[s] = acc + ba[s];
  }
  __syncthreads();
  if (tid < 64) {
    float v0 = sl[tid], v1 = sl[tid + 64];
    float m = fmaxf(v0, v1);
#pragma unroll
    for (int off = 32; off > 0; off >>= 1) m = fmaxf(m, __shfl_xor(m, off));
    float e0 = __expf(v0 - m), e1 = __expf(v1 - m);
    float s2 = e0 + e1;
#pragma unroll
    for (int off = 32; off > 0; off >>= 1) s2 += __shfl_xor(s2, off);
    float inv = 1.f / s2;
    sl[tid] = e0 * inv; sl[tid + 64] = e1 * inv;
  }
  __syncthreads();
  // xi: float4 per thread, seq split into two halves across the block
  int cix = tid & 127;        // column quad 0..127 -> cols 4*cix..4*cix+3
  int ph = tid >> 7;          // seq half 0/1
  const float* xrow = x + (size_t)b * SEQL * IND + (size_t)ph * 64 * IND;
  float4 a = {0.f, 0.f, 0.f, 0.f};
#pragma unroll 4
  for (int s = 0; s < 64; ++s) {
    float w = sl[ph * 64 + s];
    float4 v = *(const float4*)(xrow + s * IND + 4 * cix);
    a.x += w * v.x; a.y += w * v.y; a.z += w * v.z; a.w += w * v.w;
  }
  *(float4*)(&sxi[ph][4 * cix]) = a;
  __syncthreads();
  if (tid < 128) {
    float4 s0 = *(const float4*)(&sxi[0][4 * tid]);
    float4 s1 = *(const float4*)(&sxi[1][4 * tid]);
    float4 r;
    r.x = s0.x + s1.x; r.y = s0.y + s1.y; r.z = s0.z + s1.z; r.w = s0.w + s1.w;
    // xi occupies k-quads 0..127: A4[tid][b]
    *(float4*)(A + (size_t)tid * 1024 + b * 4) = r;
  }
}

// ---- per step: gates GEMV-per-(b,j) + lane-local cell update ----
// Block j (0..511) owns hidden unit j = all 4 gate rows (i,f,g,o).
// Lane = batch. W reads are wave-uniform -> scalar loads; A reads coalesced
// dwordx4 from the A4 layout. No LDS, no barriers in the K-loop.
__global__ __launch_bounds__(256) void k_gates(
    const float* __restrict__ W_ih, const float* __restrict__ W_hh,
    const float* __restrict__ b_ih, const float* __restrict__ b_hh,
    const float* __restrict__ A, float* __restrict__ c,
    float* __restrict__ out, float* __restrict__ An, int tstep) {
  int j = blockIdx.x;
  int b = threadIdx.x;
  const float* wi0 = W_ih + (size_t)j * IND;
  const float* wf0 = W_ih + (size_t)(HID + j) * IND;
  const float* wg0 = W_ih + (size_t)(2 * HID + j) * IND;
  const float* wo0 = W_ih + (size_t)(3 * HID + j) * IND;
  const float* wi1 = W_hh + (size_t)j * HID;
  const float* wf1 = W_hh + (size_t)(HID + j) * HID;
  const float* wg1 = W_hh + (size_t)(2 * HID + j) * HID;
  const float* wo1 = W_hh + (size_t)(3 * HID + j) * HID;
  float ai = 0.f, af = 0.f, ag = 0.f, ao = 0.f;
  const float4* Ab = (const float4*)A + b;   // A4[kq][b] : stride 256 float4
  // x-part: k-quads 0..127
#pragma unroll 4
  for (int kq = 0; kq < 128; ++kq) {
    float4 a = Ab[(size_t)kq * 256];
    float4 vi = *(const float4*)(wi0 + 4 * kq);
    float4 vf = *(const float4*)(wf0 + 4 * kq);
    float4 vg = *(const float4*)(wg0 + 4 * kq);
    float4 vo = *(const float4*)(wo0 + 4 * kq);
    ai += a.x * vi.x + a.y * vi.y + a.z * vi.z + a.w * vi.w;
    af += a.x * vf.x + a.y * vf.y + a.z * vf.z + a.w * vf.w;
    ag += a.x * vg.x + a.y * vg.y + a.z * vg.z + a.w * vg.w;
    ao += a.x * vo.x + a.y * vo.y + a.z * vo.z + a.w * vo.w;
  }
  // h-part: k-quads 128..255
#pragma unroll 4
  for (int kq = 0; kq < 128; ++kq) {
    float4 a = Ab[(size_t)(128 + kq) * 256];
    float4 vi = *(const float4*)(wi1 + 4 * kq);
    float4 vf = *(const float4*)(wf1 + 4 * kq);
    float4 vg = *(const float4*)(wg1 + 4 * kq);
    float4 vo = *(const float4*)(wo1 + 4 * kq);
    ai += a.x * vi.x + a.y * vi.y + a.z * vi.z + a.w * vi.w;
    af += a.x * vf.x + a.y * vf.y + a.z * vf.z + a.w * vf.w;
    ag += a.x * vg.x + a.y * vg.y + a.z * vg.z + a.w * vg.w;
    ao += a.x * vo.x + a.y * vo.y + a.z * vo.z + a.w * vo.w;
  }
  // lane-local cell update: this lane owns all 4 gates of (b, j)
  float bi = b_ih[j] + b_hh[j];
  float bf = b_ih[HID + j] + b_hh[HID + j];
  float bg = b_ih[2 * HID + j] + b_hh[2 * HID + j];
  float bo = b_ih[3 * HID + j] + b_hh[3 * HID + j];
  float ig = sigm(ai + bi);
  float fg = sigm(af + bf);
  float gg = tanhf(ag + bg);
  float og = sigm(ao + bo);
  float co = c[b * HID + j];
  float cn = fg * co + ig * gg;
  float hv = og * tanhf(cn);
  c[b * HID + j] = cn;
  out[((size_t)b * SEQL + tstep) * HID + j] = hv;
  int k = IND + j;
  An[(size_t)(k >> 2) * 1024 + b * 4 + (k & 3)] = hv;
}

extern "C" void kernel_launch(void* const* d_in, const int* in_sizes, int n_in,
                              void* d_out, int out_size, void* d_ws, size_t ws_size,
                              hipStream_t stream) {
  (void)in_sizes; (void)n_in; (void)out_size; (void)ws_size;
  const float* x    = (const float*)d_in[0];
  const float* W_ih = (const float*)d_in[1];
  const float* W_hh = (const float*)d_in[2];
  const float* b_ih = (const float*)d_in[3];
  const float* b_hh = (const float*)d_in[4];
  const float* Wa   = (const float*)d_in[5];
  const float* ba   = (const float*)d_in[6];
  float* out = (float*)d_out;

  // ws footprint: 2.5 MiB (proven-good size).
  char* p = (char*)d_ws;
  auto carve = [&](size_t bytes) { char* r = p; p += (bytes + 255) & ~(size_t)255; return r; };
  float* c  = (float*)carve((size_t)BDIM * HID * 4);
  float* A0 = (float*)carve((size_t)BDIM * KDIM * 4);
  float* A1 = (float*)carve((size_t)BDIM * KDIM * 4);

  k_init<<<BDIM, 256, 0, stream>>>(b_ih, b_hh, c, A0);

  for (int t = 0; t < 128; ++t) {
    float* R = (t & 1) ? A1 : A0;  // acts read this step (xi | h)
    float* D = (t & 1) ? A0 : A1;  // h destination (next step's buffer)
    k_attn<<<BDIM, 256, 0, stream>>>(c, Wa, ba, x, R);
    k_gates<<<512, 256, 0, stream>>>(W_ih, W_hh, b_ih, b_hh, R, c, out, D, t);
  }
}